// Round 1
// baseline (2884.202 us; speedup 1.0000x reference)
//
#include <hip/hip_runtime.h>

#define LL 8
#define BB 32
#define SS 512
#define DD 256
#define EE 2048
#define LED (LL*DD*EE)   // 4194304
#define LE  (LL*EE)      // 16384

// ---------------------------------------------------------------------------
// Kernel 1: transpose embed (L,D,E) -> embed_t (L,E,D) and accumulate norms
// ---------------------------------------------------------------------------
__global__ void transpose_norms_kernel(const float* __restrict__ embed,
                                       float* __restrict__ embed_t,
                                       float* __restrict__ norms) {
    __shared__ float tile[32][33];
    const int l  = blockIdx.z;
    const int d0 = blockIdx.y * 32;
    const int e0 = blockIdx.x * 32;
    const int tx = threadIdx.x, ty = threadIdx.y;

    float v = embed[((size_t)l*DD + d0 + ty)*EE + e0 + tx];
    tile[ty][tx] = v;
    __syncthreads();
    // embed_t[l][e0+ty][d0+tx] = embed[l][d0+tx][e0+ty]
    embed_t[((size_t)l*EE + e0 + ty)*DD + d0 + tx] = tile[tx][ty];
    __syncthreads();
    tile[ty][tx] = v * v;     // (d = d0+ty, e = e0+tx)
    __syncthreads();
    if (ty == 0) {
        float s = 0.f;
        #pragma unroll
        for (int i = 0; i < 32; ++i) s += tile[i][tx];
        atomicAdd(&norms[l*EE + e0 + tx], s);
    }
}

// ---------------------------------------------------------------------------
// Kernel 2: fused fp32 GEMM + argmin.
//   score(row, e) = ||w_e||^2 - 2 * x_row . w_e   (xx term constant per row)
// Block: 256 threads, tile 64 rows x 64 cols, K=256 resident A, dbuf B.
// ---------------------------------------------------------------------------
__global__ __launch_bounds__(256, 2)
void argmin_kernel(const float* __restrict__ x,
                   const float* __restrict__ embed,
                   const float* __restrict__ norms,
                   int* __restrict__ ids_out) {
    __shared__ float As[DD][64];       // 64 KB, As[k][m]
    __shared__ float Bs[2][32][64];    // 16 KB

    const int blk  = blockIdx.x;
    const int l    = blk & 7;          // XCD-aligned per-l placement
    const int tile = blk >> 3;         // 0..255
    const int b    = tile >> 3;
    const int s0   = (tile & 7) << 6;
    const size_t row0 = ((size_t)(b*LL + l)*SS + s0);
    const int tid = threadIdx.x;
    const int ty  = tid >> 4;          // 0..15 (rows / 4)
    const int tx  = tid & 15;          // 0..15 (cols / 4)

    // ---- load A tile: 64 rows x 256 k, store transposed As[k][m] ----
    const float4* x4 = (const float4*)(x + row0*DD);
    #pragma unroll
    for (int i = 0; i < 16; ++i) {
        int flat = i*256 + tid;
        int m  = flat >> 6;            // row 0..63 (uniform per wave)
        int kq = flat & 63;            // float4 index within row
        float4 v = x4[m*64 + kq];
        As[kq*4+0][m] = v.x;
        As[kq*4+1][m] = v.y;
        As[kq*4+2][m] = v.z;
        As[kq*4+3][m] = v.w;
    }

    const float* Bsrc = embed + (size_t)l*DD*EE;   // embed[l][k][e]

    float minv[4] = {3.4e38f, 3.4e38f, 3.4e38f, 3.4e38f};
    int   mini[4] = {0, 0, 0, 0};

    for (int et = 0; et < 32; ++et) {
        const int e0 = et * 64;
        float acc[4][4];
        #pragma unroll
        for (int i = 0; i < 4; ++i)
            #pragma unroll
            for (int j = 0; j < 4; ++j) acc[i][j] = 0.f;

        // prime chunk 0 (k = 0..31)
        #pragma unroll
        for (int j = 0; j < 8; ++j) {
            int flat = j*256 + tid;
            int kk = flat >> 6, ee = flat & 63;
            Bs[0][kk][ee] = Bsrc[(size_t)kk*EE + e0 + ee];
        }
        __syncthreads();

        for (int kc = 0; kc < 8; ++kc) {
            const int cur = kc & 1;
            float breg[8];
            if (kc < 7) {
                #pragma unroll
                for (int j = 0; j < 8; ++j) {
                    int flat = j*256 + tid;
                    int kk = flat >> 6, ee = flat & 63;
                    breg[j] = Bsrc[(size_t)((kc+1)*32 + kk)*EE + e0 + ee];
                }
            }
            #pragma unroll
            for (int kk = 0; kk < 32; ++kk) {
                const int k = kc*32 + kk;
                float4 a  = *(const float4*)&As[k][ty*4];
                float4 bv = *(const float4*)&Bs[cur][kk][tx*4];
                acc[0][0] += a.x*bv.x; acc[0][1] += a.x*bv.y; acc[0][2] += a.x*bv.z; acc[0][3] += a.x*bv.w;
                acc[1][0] += a.y*bv.x; acc[1][1] += a.y*bv.y; acc[1][2] += a.y*bv.z; acc[1][3] += a.y*bv.w;
                acc[2][0] += a.z*bv.x; acc[2][1] += a.z*bv.y; acc[2][2] += a.z*bv.z; acc[2][3] += a.z*bv.w;
                acc[3][0] += a.w*bv.x; acc[3][1] += a.w*bv.y; acc[3][2] += a.w*bv.z; acc[3][3] += a.w*bv.w;
            }
            if (kc < 7) {
                #pragma unroll
                for (int j = 0; j < 8; ++j) {
                    int flat = j*256 + tid;
                    int kk = flat >> 6, ee = flat & 63;
                    Bs[cur ^ 1][kk][ee] = breg[j];
                }
            }
            __syncthreads();
        }

        // epilogue: scores + running argmin (ascending e, strict < keeps first)
        float n0 = norms[l*EE + e0 + tx*4 + 0];
        float n1 = norms[l*EE + e0 + tx*4 + 1];
        float n2 = norms[l*EE + e0 + tx*4 + 2];
        float n3 = norms[l*EE + e0 + tx*4 + 3];
        #pragma unroll
        for (int i = 0; i < 4; ++i) {
            float s0v = n0 - 2.f*acc[i][0];
            float s1v = n1 - 2.f*acc[i][1];
            float s2v = n2 - 2.f*acc[i][2];
            float s3v = n3 - 2.f*acc[i][3];
            int e = e0 + tx*4;
            if (s0v < minv[i]) { minv[i] = s0v; mini[i] = e + 0; }
            if (s1v < minv[i]) { minv[i] = s1v; mini[i] = e + 1; }
            if (s2v < minv[i]) { minv[i] = s2v; mini[i] = e + 2; }
            if (s3v < minv[i]) { minv[i] = s3v; mini[i] = e + 3; }
        }
    }

    // ---- cross-thread argmin reduce (reuse As as scratch) ----
    __syncthreads();
    float* redv = (float*)As;          // 64*16 floats
    int*   redi = (int*)((float*)As + 1024);
    #pragma unroll
    for (int i = 0; i < 4; ++i) {
        int r = ty*4 + i;
        redv[r*16 + tx] = minv[i];
        redi[r*16 + tx] = mini[i];
    }
    __syncthreads();
    if (tid < 64) {
        int r = tid;
        float bv = redv[r*16]; int bi = redi[r*16];
        #pragma unroll
        for (int t = 1; t < 16; ++t) {
            float v = redv[r*16 + t]; int ii = redi[r*16 + t];
            if (v < bv || (v == bv && ii < bi)) { bv = v; bi = ii; }
        }
        ids_out[row0 + r] = bi;
    }
}

// ---------------------------------------------------------------------------
// Kernel 3: fused gather (out = q), diff partial, scatter (counts, embed_sum)
// 4 rows per block, 64 lanes (float4) per row.
// ---------------------------------------------------------------------------
__global__ __launch_bounds__(256)
void gather_scatter_kernel(const float* __restrict__ x,
                           const float* __restrict__ embed_t,
                           const int* __restrict__ ids,
                           float* __restrict__ out,
                           float* __restrict__ embed_sum,
                           float* __restrict__ counts,
                           float* __restrict__ diff_acc) {
    const int tid  = threadIdx.x;
    const size_t rf = (size_t)blockIdx.x*4 + (tid >> 6);
    const int lane = tid & 63;
    const int l    = (int)((rf / SS) % LL);
    const int id   = ids[rf];

    float4 xv = ((const float4*)x)[rf*64 + lane];
    float4 qv = ((const float4*)embed_t)[((size_t)l*EE + id)*64 + lane];
    ((float4*)out)[rf*64 + lane] = qv;

    float* es = embed_sum + ((size_t)l*EE + id)*DD + lane*4;
    atomicAdd(es + 0, xv.x);
    atomicAdd(es + 1, xv.y);
    atomicAdd(es + 2, xv.z);
    atomicAdd(es + 3, xv.w);
    if (lane == 0) atomicAdd(&counts[l*EE + id], 1.0f);

    if (l == LL - 1) {                 // uniform per block (4 rows same l)
        float dx = qv.x - xv.x, dy = qv.y - xv.y, dz = qv.z - xv.z, dw = qv.w - xv.w;
        float sq = dx*dx + dy*dy + dz*dz + dw*dw;
        #pragma unroll
        for (int off = 32; off; off >>= 1) sq += __shfl_down(sq, off);
        __shared__ float wsum[4];
        if (lane == 0) wsum[tid >> 6] = sq;
        __syncthreads();
        if (tid == 0) atomicAdd(diff_acc, wsum[0] + wsum[1] + wsum[2] + wsum[3]);
    }
}

// ---------------------------------------------------------------------------
// Kernel 4: new_cluster_size + per-l sum n
// ---------------------------------------------------------------------------
__global__ void finalize_cluster_kernel(const float* __restrict__ cs_in,
                                        const float* __restrict__ counts,
                                        float* __restrict__ ncs_out,
                                        float* __restrict__ n_out) {
    const int l = blockIdx.x, tid = threadIdx.x;
    float s = 0.f;
    for (int e = tid; e < EE; e += 256) {
        float v = 0.999f*cs_in[l*EE + e] + 0.001f*counts[l*EE + e];
        ncs_out[l*EE + e] = v;
        s += v;
    }
    #pragma unroll
    for (int off = 32; off; off >>= 1) s += __shfl_down(s, off);
    __shared__ float red[4];
    if ((tid & 63) == 0) red[tid >> 6] = s;
    __syncthreads();
    if (tid == 0) n_out[l] = red[0] + red[1] + red[2] + red[3];
}

// ---------------------------------------------------------------------------
// Kernel 5: new_embed_avg = 0.999*embed_avg + 0.001*embed_sum^T ; new_embed
// ---------------------------------------------------------------------------
__global__ void finalize_embed_kernel(const float* __restrict__ embed_avg,
                                      const float* __restrict__ embed_sum,
                                      const float* __restrict__ ncs,
                                      const float* __restrict__ n,
                                      float* __restrict__ nea_out,
                                      float* __restrict__ ne_out) {
    __shared__ float tile[32][33];
    const int l  = blockIdx.z;
    const int d0 = blockIdx.y * 32;
    const int e0 = blockIdx.x * 32;
    const int tx = threadIdx.x, ty = threadIdx.y;

    tile[ty][tx] = embed_sum[((size_t)l*EE + e0 + ty)*DD + d0 + tx];
    __syncthreads();
    const size_t idx = ((size_t)l*DD + d0 + ty)*EE + e0 + tx;
    float nea = 0.999f*embed_avg[idx] + 0.001f*tile[tx][ty];
    nea_out[idx] = nea;
    float nl = n[l];
    float c  = ncs[l*EE + e0 + tx];
    float cs = (c + 1e-5f) / (nl + 0.02048f) * nl;
    ne_out[idx] = nea / cs;
}

// ---------------------------------------------------------------------------
// Kernel 6: diff = (acc / (B*S*D)) * 2 / L
// ---------------------------------------------------------------------------
__global__ void diff_scale_kernel(const float* __restrict__ diff_acc,
                                  float* __restrict__ diff_out) {
    *diff_out = (*diff_acc / (float)(BB*SS*DD)) * 0.25f;
}

// ---------------------------------------------------------------------------
extern "C" void kernel_launch(void* const* d_in, const int* in_sizes, int n_in,
                              void* d_out, int out_size, void* d_ws, size_t ws_size,
                              hipStream_t stream) {
    const float* x            = (const float*)d_in[0];
    const float* embed        = (const float*)d_in[1];
    const float* cluster_size = (const float*)d_in[2];
    const float* embed_avg    = (const float*)d_in[3];

    float* out      = (float*)d_out;
    float* diff_out = out + 33554432;
    int*   ids_out  = (int*)(out + 33554433);
    float* ne_out   = out + 33685505;
    float* ncs_out  = out + 37879809;
    float* nea_out  = out + 37896193;

    float* ws        = (float*)d_ws;
    float* embed_t   = ws;                       // LED floats
    float* embed_sum = ws + LED;                 // LED floats (zeroed)
    float* counts    = ws + 2*(size_t)LED;       // LE floats  (zeroed)
    float* norms     = counts + LE;              // LE floats  (zeroed)
    float* diff_acc  = norms + LE;               // 1 float    (zeroed)
    float* n_ws      = diff_acc + 1;             // LL floats

    // zero: embed_sum .. diff_acc (contiguous)
    hipMemsetAsync(embed_sum, 0, (size_t)(LED + 2*LE + 1) * sizeof(float), stream);

    transpose_norms_kernel<<<dim3(EE/32, DD/32, LL), dim3(32, 32), 0, stream>>>(
        embed, embed_t, norms);

    argmin_kernel<<<2048, 256, 0, stream>>>(x, embed, norms, ids_out);

    gather_scatter_kernel<<<BB*LL*SS/4, 256, 0, stream>>>(
        x, embed_t, ids_out, out, embed_sum, counts, diff_acc);

    finalize_cluster_kernel<<<LL, 256, 0, stream>>>(cluster_size, counts, ncs_out, n_ws);

    finalize_embed_kernel<<<dim3(EE/32, DD/32, LL), dim3(32, 32), 0, stream>>>(
        embed_avg, embed_sum, ncs_out, n_ws, nea_out, ne_out);

    diff_scale_kernel<<<1, 1, 0, stream>>>(diff_acc, diff_out);
}

// Round 2
// 1219.538 us; speedup vs baseline: 2.3650x; 2.3650x over previous
//
#include <hip/hip_runtime.h>

#define LL 8
#define BB 32
#define SS 512
#define DD 256
#define EE 2048
#define LED (LL*DD*EE)   // 4194304
#define LE  (LL*EE)      // 16384
#define NKS 17           // 16 real K-steps + 1 norm-fold K-step

typedef __bf16 bf16x8 __attribute__((ext_vector_type(8)));
typedef float  f32x16 __attribute__((ext_vector_type(16)));

// ---------------------------------------------------------------------------
// Kernel 1: transpose embed (L,D,E) -> embed_t (L,E,D) and accumulate norms
// ---------------------------------------------------------------------------
__global__ void transpose_norms_kernel(const float* __restrict__ embed,
                                       float* __restrict__ embed_t,
                                       float* __restrict__ norms) {
    __shared__ float tile[32][33];
    const int l  = blockIdx.z;
    const int d0 = blockIdx.y * 32;
    const int e0 = blockIdx.x * 32;
    const int tx = threadIdx.x, ty = threadIdx.y;

    float v = embed[((size_t)l*DD + d0 + ty)*EE + e0 + tx];
    tile[ty][tx] = v;
    __syncthreads();
    embed_t[((size_t)l*EE + e0 + ty)*DD + d0 + tx] = tile[tx][ty];
    __syncthreads();
    tile[ty][tx] = v * v;
    __syncthreads();
    if (ty == 0) {
        float s = 0.f;
        #pragma unroll
        for (int i = 0; i < 32; ++i) s += tile[i][tx];
        atomicAdd(&norms[l*EE + e0 + tx], s);
    }
}

// ---------------------------------------------------------------------------
// Kernel 1b: convert embed -> MFMA A-fragment-ordered bf16 hi/lo, with the
// 17th K-step holding (-norms/2) as a bf16 hi/lo pair (times ones on B side).
// Layout: frag[l][mtile64][part2][kstep17][lane64][8 bf16]
// A-frag (32x32x16): A[m = lane&31][k = kstep*16 + (lane>>5)*8 + j]
// ---------------------------------------------------------------------------
__global__ void prep_embed_frag(const float* __restrict__ embed,
                                const float* __restrict__ norms,
                                __bf16* __restrict__ frag) {
    const int bid   = blockIdx.x;
    const int kstep = bid % NKS;
    const int mtile = (bid / NKS) % 64;
    const int l     = bid / (NKS * 64);
    const int lane  = threadIdx.x;
    const int e     = mtile*32 + (lane & 31);
    const int kbase = kstep*16 + (lane >> 5)*8;

    bf16x8 vh, vl;
    if (kstep < 16) {
        #pragma unroll
        for (int j = 0; j < 8; ++j) {
            float v = embed[((size_t)l*DD + kbase + j)*EE + e];
            __bf16 h = (__bf16)v;
            vh[j] = h;
            vl[j] = (__bf16)(v - (float)h);
        }
    } else {
        #pragma unroll
        for (int j = 0; j < 8; ++j) { vh[j] = (__bf16)0.0f; vl[j] = (__bf16)0.0f; }
        if (kbase == 256) {              // lanes 0..31 carry k=256,257
            float nv = -0.5f * norms[l*EE + e];
            __bf16 ch = (__bf16)nv;
            vh[0] = ch;
            vh[1] = (__bf16)(nv - (float)ch);
        }
    }
    size_t base = ((((size_t)l*64 + mtile)*2 + 0)*NKS + kstep)*64 + lane;
    *(bf16x8*)(frag + base*8) = vh;
    base = ((((size_t)l*64 + mtile)*2 + 1)*NKS + kstep)*64 + lane;
    *(bf16x8*)(frag + base*8) = vl;
}

// ---------------------------------------------------------------------------
// Kernel 2: MFMA argmin. D = embed_frags(A, m=e) x x_frags(B, n=row).
// Block = 4 waves x 32 rows = 128 rows; sweep all 64 e-mtiles.
// score = x.w - |w|^2/2 (argmax == argmin of dist); norms folded into K-step 17.
// x converted to split-bf16 B-frags in registers (read once).
// ---------------------------------------------------------------------------
__global__ __launch_bounds__(256, 2)
void argmin_mfma(const float* __restrict__ x,
                 const __bf16* __restrict__ frag,
                 int* __restrict__ ids_out) {
    __shared__ __bf16 smem[2][2*NKS*512];    // 2 bufs x (hi+lo) x 17 ksteps x 1KB = 68 KB

    const int tid  = threadIdx.x;
    const int wave = tid >> 6, lane = tid & 63;
    const int l    = blockIdx.x & 7;          // XCD-aligned: frag slice L2-resident
    const int rb   = blockIdx.x >> 3;         // 0..127
    const int idx  = rb*4 + wave;             // 0..511
    const int b    = idx >> 4, st = idx & 15;
    const int rowtile = (b*LL + l)*16 + st;   // global 32-row tile

    // ---- x rows -> split-bf16 B-fragments (registers). B[k][n=lane&31] ----
    bf16x8 bh[NKS], bl[NKS];
    {
        const float* xr = x + (size_t)(rowtile*32 + (lane & 31))*DD + (lane >> 5)*8;
        #pragma unroll
        for (int ks = 0; ks < 16; ++ks) {
            float4 v0 = *(const float4*)(xr + ks*16);
            float4 v1 = *(const float4*)(xr + ks*16 + 4);
            float f[8] = {v0.x, v0.y, v0.z, v0.w, v1.x, v1.y, v1.z, v1.w};
            #pragma unroll
            for (int j = 0; j < 8; ++j) {
                __bf16 h = (__bf16)f[j];
                bh[ks][j] = h;
                bl[ks][j] = (__bf16)(f[j] - (float)h);
            }
        }
        #pragma unroll
        for (int j = 0; j < 8; ++j) { bh[16][j] = (__bf16)0.0f; bl[16][j] = (__bf16)0.0f; }
        if (lane < 32) { bh[16][0] = (__bf16)1.0f; bh[16][1] = (__bf16)1.0f; }
    }

    const __bf16* fl = frag + (size_t)l*64*2*NKS*512;

    auto stage = [&](int m, int buf) {
        const __bf16* src = fl + (size_t)m*2*NKS*512;
        __bf16* dst = &smem[buf][0];
        for (int i = wave; i < 2*NKS; i += 4) {
            __builtin_amdgcn_global_load_lds(
                (const __attribute__((address_space(1))) void*)(src + i*512 + lane*8),
                (__attribute__((address_space(3))) void*)(dst + i*512), 16, 0, 0);
        }
    };

    float maxv = -3.4e38f;
    int   maxi = 0;

    stage(0, 0);
    __syncthreads();
    for (int m = 0; m < 64; ++m) {
        const int buf = m & 1;
        if (m < 63) stage(m + 1, buf ^ 1);
        const __bf16* sA = &smem[buf][0];
        f32x16 acc;
        #pragma unroll
        for (int i = 0; i < 16; ++i) acc[i] = 0.0f;
        #pragma unroll
        for (int ks = 0; ks < NKS; ++ks) {
            bf16x8 ah = *(const bf16x8*)(sA + ks*512 + lane*8);
            bf16x8 al = *(const bf16x8*)(sA + (NKS + ks)*512 + lane*8);
            acc = __builtin_amdgcn_mfma_f32_32x32x16_bf16(ah, bh[ks], acc, 0, 0, 0);
            acc = __builtin_amdgcn_mfma_f32_32x32x16_bf16(ah, bl[ks], acc, 0, 0, 0);
            acc = __builtin_amdgcn_mfma_f32_32x32x16_bf16(al, bh[ks], acc, 0, 0, 0);
        }
        // C/D: col = lane&31 (x-row), row(e) = (r&3) + 8*(r>>2) + 4*(lane>>5)
        #pragma unroll
        for (int r = 0; r < 16; ++r) {
            int e = m*32 + (r & 3) + 8*(r >> 2) + 4*(lane >> 5);
            float v = acc[r];
            if (v > maxv || (v == maxv && e < maxi)) { maxv = v; maxi = e; }
        }
        __syncthreads();
    }
    // merge the two e-halves held by lane and lane^32 (same x-row)
    float ov = __shfl_xor(maxv, 32, 64);
    int   oi = __shfl_xor(maxi, 32, 64);
    if (ov > maxv || (ov == maxv && oi < maxi)) { maxv = ov; maxi = oi; }
    if (lane < 32) ids_out[(size_t)rowtile*32 + lane] = maxi;
}

// ---------------------------------------------------------------------------
// Kernel 3: fused gather (out = q), diff partial, scatter (counts, embed_sum)
// ---------------------------------------------------------------------------
__global__ __launch_bounds__(256)
void gather_scatter_kernel(const float* __restrict__ x,
                           const float* __restrict__ embed_t,
                           const int* __restrict__ ids,
                           float* __restrict__ out,
                           float* __restrict__ embed_sum,
                           float* __restrict__ counts,
                           float* __restrict__ diff_acc) {
    const int tid  = threadIdx.x;
    const size_t rf = (size_t)blockIdx.x*4 + (tid >> 6);
    const int lane = tid & 63;
    const int l    = (int)((rf / SS) % LL);
    const int id   = ids[rf];

    float4 xv = ((const float4*)x)[rf*64 + lane];
    float4 qv = ((const float4*)embed_t)[((size_t)l*EE + id)*64 + lane];
    ((float4*)out)[rf*64 + lane] = qv;

    float* es = embed_sum + ((size_t)l*EE + id)*DD + lane*4;
    atomicAdd(es + 0, xv.x);
    atomicAdd(es + 1, xv.y);
    atomicAdd(es + 2, xv.z);
    atomicAdd(es + 3, xv.w);
    if (lane == 0) atomicAdd(&counts[l*EE + id], 1.0f);

    if (l == LL - 1) {
        float dx = qv.x - xv.x, dy = qv.y - xv.y, dz = qv.z - xv.z, dw = qv.w - xv.w;
        float sq = dx*dx + dy*dy + dz*dz + dw*dw;
        #pragma unroll
        for (int off = 32; off; off >>= 1) sq += __shfl_down(sq, off);
        __shared__ float wsum[4];
        if (lane == 0) wsum[tid >> 6] = sq;
        __syncthreads();
        if (tid == 0) atomicAdd(diff_acc, wsum[0] + wsum[1] + wsum[2] + wsum[3]);
    }
}

// ---------------------------------------------------------------------------
// Kernel 4: new_cluster_size + per-l sum n
// ---------------------------------------------------------------------------
__global__ void finalize_cluster_kernel(const float* __restrict__ cs_in,
                                        const float* __restrict__ counts,
                                        float* __restrict__ ncs_out,
                                        float* __restrict__ n_out) {
    const int l = blockIdx.x, tid = threadIdx.x;
    float s = 0.f;
    for (int e = tid; e < EE; e += 256) {
        float v = 0.999f*cs_in[l*EE + e] + 0.001f*counts[l*EE + e];
        ncs_out[l*EE + e] = v;
        s += v;
    }
    #pragma unroll
    for (int off = 32; off; off >>= 1) s += __shfl_down(s, off);
    __shared__ float red[4];
    if ((tid & 63) == 0) red[tid >> 6] = s;
    __syncthreads();
    if (tid == 0) n_out[l] = red[0] + red[1] + red[2] + red[3];
}

// ---------------------------------------------------------------------------
// Kernel 5: new_embed_avg = 0.999*embed_avg + 0.001*embed_sum^T ; new_embed
// ---------------------------------------------------------------------------
__global__ void finalize_embed_kernel(const float* __restrict__ embed_avg,
                                      const float* __restrict__ embed_sum,
                                      const float* __restrict__ ncs,
                                      const float* __restrict__ n,
                                      float* __restrict__ nea_out,
                                      float* __restrict__ ne_out) {
    __shared__ float tile[32][33];
    const int l  = blockIdx.z;
    const int d0 = blockIdx.y * 32;
    const int e0 = blockIdx.x * 32;
    const int tx = threadIdx.x, ty = threadIdx.y;

    tile[ty][tx] = embed_sum[((size_t)l*EE + e0 + ty)*DD + d0 + tx];
    __syncthreads();
    const size_t idx = ((size_t)l*DD + d0 + ty)*EE + e0 + tx;
    float nea = 0.999f*embed_avg[idx] + 0.001f*tile[tx][ty];
    nea_out[idx] = nea;
    float nl = n[l];
    float c  = ncs[l*EE + e0 + tx];
    float cs = (c + 1e-5f) / (nl + 0.02048f) * nl;
    ne_out[idx] = nea / cs;
}

// ---------------------------------------------------------------------------
// Kernel 6: diff = (acc / (B*S*D)) * 2 / L
// ---------------------------------------------------------------------------
__global__ void diff_scale_kernel(const float* __restrict__ diff_acc,
                                  float* __restrict__ diff_out) {
    *diff_out = (*diff_acc / (float)(BB*SS*DD)) * 0.25f;
}

// ---------------------------------------------------------------------------
extern "C" void kernel_launch(void* const* d_in, const int* in_sizes, int n_in,
                              void* d_out, int out_size, void* d_ws, size_t ws_size,
                              hipStream_t stream) {
    const float* x            = (const float*)d_in[0];
    const float* embed        = (const float*)d_in[1];
    const float* cluster_size = (const float*)d_in[2];
    const float* embed_avg    = (const float*)d_in[3];

    float* out      = (float*)d_out;
    float* diff_out = out + 33554432;
    int*   ids_out  = (int*)(out + 33554433);
    float* ne_out   = out + 33685505;
    float* ncs_out  = out + 37879809;
    float* nea_out  = out + 37896193;

    float* ws        = (float*)d_ws;
    float* embed_t   = ws;                         // LED floats
    float* embed_sum = ws + LED;                   // LED floats (zeroed)
    float* counts    = ws + 2*(size_t)LED;         // LE floats  (zeroed)
    float* norms     = counts + LE;                // LE floats  (zeroed)
    float* diff_acc  = norms + LE;                 // 1 float    (zeroed)
    float* n_ws      = diff_acc + 1;               // LL floats
    __bf16* embfrag  = (__bf16*)(ws + 2*(size_t)LED + 2*LE + 16);  // 8.9M bf16

    hipMemsetAsync(embed_sum, 0, (size_t)(LED + 2*LE + 1) * sizeof(float), stream);

    transpose_norms_kernel<<<dim3(EE/32, DD/32, LL), dim3(32, 32), 0, stream>>>(
        embed, embed_t, norms);

    prep_embed_frag<<<LL*64*NKS, 64, 0, stream>>>(embed, norms, embfrag);

    argmin_mfma<<<1024, 256, 0, stream>>>(x, embfrag, ids_out);

    gather_scatter_kernel<<<BB*LL*SS/4, 256, 0, stream>>>(
        x, embed_t, ids_out, out, embed_sum, counts, diff_acc);

    finalize_cluster_kernel<<<LL, 256, 0, stream>>>(cluster_size, counts, ncs_out, n_ws);

    finalize_embed_kernel<<<dim3(EE/32, DD/32, LL), dim3(32, 32), 0, stream>>>(
        embed_avg, embed_sum, ncs_out, n_ws, nea_out, ne_out);

    diff_scale_kernel<<<1, 1, 0, stream>>>(diff_acc, diff_out);
}

// Round 3
// 926.710 us; speedup vs baseline: 3.1123x; 1.3160x over previous
//
#include <hip/hip_runtime.h>

#define LL 8
#define BB 32
#define SS 512
#define DD 256
#define EE 2048
#define LED (LL*DD*EE)   // 4194304
#define LE  (LL*EE)      // 16384
#define NROWS (BB*LL*SS) // 131072
#define NKS 17           // 16 real K-steps + 1 norm-fold K-step

typedef __bf16 bf16x8 __attribute__((ext_vector_type(8)));
typedef float  f32x16 __attribute__((ext_vector_type(16)));

// ---------------------------------------------------------------------------
// Kernel 1: transpose embed (L,D,E) -> embed_t (L,E,D) and accumulate norms
// ---------------------------------------------------------------------------
__global__ void transpose_norms_kernel(const float* __restrict__ embed,
                                       float* __restrict__ embed_t,
                                       float* __restrict__ norms) {
    __shared__ float tile[32][33];
    const int l  = blockIdx.z;
    const int d0 = blockIdx.y * 32;
    const int e0 = blockIdx.x * 32;
    const int tx = threadIdx.x, ty = threadIdx.y;

    float v = embed[((size_t)l*DD + d0 + ty)*EE + e0 + tx];
    tile[ty][tx] = v;
    __syncthreads();
    embed_t[((size_t)l*EE + e0 + ty)*DD + d0 + tx] = tile[tx][ty];
    __syncthreads();
    tile[ty][tx] = v * v;
    __syncthreads();
    if (ty == 0) {
        float s = 0.f;
        #pragma unroll
        for (int i = 0; i < 32; ++i) s += tile[i][tx];
        atomicAdd(&norms[l*EE + e0 + tx], s);
    }
}

// ---------------------------------------------------------------------------
// Kernel 1b: embed -> MFMA A-fragment-ordered bf16 hi/lo (+ norm fold K-step)
// ---------------------------------------------------------------------------
__global__ void prep_embed_frag(const float* __restrict__ embed,
                                const float* __restrict__ norms,
                                __bf16* __restrict__ frag) {
    const int bid   = blockIdx.x;
    const int kstep = bid % NKS;
    const int mtile = (bid / NKS) % 64;
    const int l     = bid / (NKS * 64);
    const int lane  = threadIdx.x;
    const int e     = mtile*32 + (lane & 31);
    const int kbase = kstep*16 + (lane >> 5)*8;

    bf16x8 vh, vl;
    if (kstep < 16) {
        #pragma unroll
        for (int j = 0; j < 8; ++j) {
            float v = embed[((size_t)l*DD + kbase + j)*EE + e];
            __bf16 h = (__bf16)v;
            vh[j] = h;
            vl[j] = (__bf16)(v - (float)h);
        }
    } else {
        #pragma unroll
        for (int j = 0; j < 8; ++j) { vh[j] = (__bf16)0.0f; vl[j] = (__bf16)0.0f; }
        if (kbase == 256) {
            float nv = -0.5f * norms[l*EE + e];
            __bf16 ch = (__bf16)nv;
            vh[0] = ch;
            vh[1] = (__bf16)(nv - (float)ch);
        }
    }
    size_t base = ((((size_t)l*64 + mtile)*2 + 0)*NKS + kstep)*64 + lane;
    *(bf16x8*)(frag + base*8) = vh;
    base = ((((size_t)l*64 + mtile)*2 + 1)*NKS + kstep)*64 + lane;
    *(bf16x8*)(frag + base*8) = vl;
}

// ---------------------------------------------------------------------------
// Kernel 2: MFMA argmin + fused counts histogram.
// ---------------------------------------------------------------------------
__global__ __launch_bounds__(256, 2)
void argmin_mfma(const float* __restrict__ x,
                 const __bf16* __restrict__ frag,
                 int* __restrict__ ids_out,
                 int* __restrict__ counts_i) {
    __shared__ __bf16 smem[2][2*NKS*512];    // 68 KB

    const int tid  = threadIdx.x;
    const int wave = tid >> 6, lane = tid & 63;
    const int l    = blockIdx.x & 7;
    const int rb   = blockIdx.x >> 3;
    const int idx  = rb*4 + wave;
    const int b    = idx >> 4, st = idx & 15;
    const int rowtile = (b*LL + l)*16 + st;

    bf16x8 bh[NKS], bl[NKS];
    {
        const float* xr = x + (size_t)(rowtile*32 + (lane & 31))*DD + (lane >> 5)*8;
        #pragma unroll
        for (int ks = 0; ks < 16; ++ks) {
            float4 v0 = *(const float4*)(xr + ks*16);
            float4 v1 = *(const float4*)(xr + ks*16 + 4);
            float f[8] = {v0.x, v0.y, v0.z, v0.w, v1.x, v1.y, v1.z, v1.w};
            #pragma unroll
            for (int j = 0; j < 8; ++j) {
                __bf16 h = (__bf16)f[j];
                bh[ks][j] = h;
                bl[ks][j] = (__bf16)(f[j] - (float)h);
            }
        }
        #pragma unroll
        for (int j = 0; j < 8; ++j) { bh[16][j] = (__bf16)0.0f; bl[16][j] = (__bf16)0.0f; }
        if (lane < 32) { bh[16][0] = (__bf16)1.0f; bh[16][1] = (__bf16)1.0f; }
    }

    const __bf16* fl = frag + (size_t)l*64*2*NKS*512;

    auto stage = [&](int m, int buf) {
        const __bf16* src = fl + (size_t)m*2*NKS*512;
        __bf16* dst = &smem[buf][0];
        for (int i = wave; i < 2*NKS; i += 4) {
            __builtin_amdgcn_global_load_lds(
                (const __attribute__((address_space(1))) void*)(src + i*512 + lane*8),
                (__attribute__((address_space(3))) void*)(dst + i*512), 16, 0, 0);
        }
    };

    float maxv = -3.4e38f;
    int   maxi = 0;

    stage(0, 0);
    __syncthreads();
    for (int m = 0; m < 64; ++m) {
        const int buf = m & 1;
        if (m < 63) stage(m + 1, buf ^ 1);
        const __bf16* sA = &smem[buf][0];
        f32x16 acc;
        #pragma unroll
        for (int i = 0; i < 16; ++i) acc[i] = 0.0f;
        #pragma unroll
        for (int ks = 0; ks < NKS; ++ks) {
            bf16x8 ah = *(const bf16x8*)(sA + ks*512 + lane*8);
            bf16x8 al = *(const bf16x8*)(sA + (NKS + ks)*512 + lane*8);
            acc = __builtin_amdgcn_mfma_f32_32x32x16_bf16(ah, bh[ks], acc, 0, 0, 0);
            acc = __builtin_amdgcn_mfma_f32_32x32x16_bf16(ah, bl[ks], acc, 0, 0, 0);
            acc = __builtin_amdgcn_mfma_f32_32x32x16_bf16(al, bh[ks], acc, 0, 0, 0);
        }
        #pragma unroll
        for (int r = 0; r < 16; ++r) {
            int e = m*32 + (r & 3) + 8*(r >> 2) + 4*(lane >> 5);
            float v = acc[r];
            if (v > maxv || (v == maxv && e < maxi)) { maxv = v; maxi = e; }
        }
        __syncthreads();
    }
    float ov = __shfl_xor(maxv, 32, 64);
    int   oi = __shfl_xor(maxi, 32, 64);
    if (ov > maxv || (ov == maxv && oi < maxi)) { maxv = ov; maxi = oi; }
    if (lane < 32) {
        ids_out[(size_t)rowtile*32 + lane] = maxi;
        atomicAdd(&counts_i[l*EE + maxi], 1);
    }
}

// ---------------------------------------------------------------------------
// Kernel 2b: per-l exclusive scan of counts -> bin_start, cursor
// ---------------------------------------------------------------------------
__global__ __launch_bounds__(256)
void scan_kernel(const int* __restrict__ counts_i,
                 int* __restrict__ bin_start,
                 int* __restrict__ cursor) {
    __shared__ int part[256];
    const int l = blockIdx.x, tid = threadIdx.x;
    const int base = l*EE + tid*8;
    int local[8], tsum = 0;
    #pragma unroll
    for (int j = 0; j < 8; ++j) { local[j] = counts_i[base + j]; tsum += local[j]; }
    part[tid] = tsum;
    __syncthreads();
    for (int off = 1; off < 256; off <<= 1) {
        int v = (tid >= off) ? part[tid - off] : 0;
        __syncthreads();
        part[tid] += v;
        __syncthreads();
    }
    int run = part[tid] - tsum;
    #pragma unroll
    for (int j = 0; j < 8; ++j) {
        bin_start[base + j] = run;
        cursor[base + j]    = run;
        run += local[j];
    }
}

// ---------------------------------------------------------------------------
// Kernel 2c: scatter row indices into per-l sorted order
// ---------------------------------------------------------------------------
__global__ __launch_bounds__(256)
void scatter_idx_kernel(const int* __restrict__ ids,
                        int* __restrict__ cursor,
                        int* __restrict__ sorted_rows) {
    const int r = blockIdx.x*256 + threadIdx.x;
    const int l = (r >> 9) & 7;
    const int e = ids[r];
    int pos = atomicAdd(&cursor[l*EE + e], 1);
    sorted_rows[l*(NROWS/LL) + pos] = r;
}

// ---------------------------------------------------------------------------
// Kernel 2d: segmented sum — one block per (l,e), threads = d
// ---------------------------------------------------------------------------
__global__ __launch_bounds__(256)
void segsum_kernel(const float* __restrict__ x,
                   const int* __restrict__ sorted_rows,
                   const int* __restrict__ bin_start,
                   const int* __restrict__ counts_i,
                   float* __restrict__ embed_sum) {
    const int bid = blockIdx.x;
    const int l   = bid >> 11;
    const int e   = bid & 2047;
    const int tid = threadIdx.x;
    const int start = bin_start[l*EE + e];
    const int cnt   = counts_i[l*EE + e];
    const int* rows = sorted_rows + l*(NROWS/LL);

    float acc = 0.f;
    int i = 0;
    for (; i + 1 < cnt; i += 2) {
        int r0 = rows[start + i], r1 = rows[start + i + 1];
        acc += x[(size_t)r0*DD + tid] + x[(size_t)r1*DD + tid];
    }
    if (i < cnt) acc += x[(size_t)rows[start + i]*DD + tid];
    embed_sum[((size_t)l*EE + e)*DD + tid] = acc;
}

// ---------------------------------------------------------------------------
// Kernel 3: out = q gather + diff partial (x read only for l == L-1)
// ---------------------------------------------------------------------------
__global__ __launch_bounds__(256)
void gather_out_kernel(const float* __restrict__ x,
                       const float* __restrict__ embed_t,
                       const int* __restrict__ ids,
                       float* __restrict__ out,
                       float* __restrict__ diff_acc) {
    const int tid  = threadIdx.x;
    const size_t rf = (size_t)blockIdx.x*4 + (tid >> 6);
    const int lane = tid & 63;
    const int l    = (int)((rf >> 9) & 7);
    const int id   = ids[rf];

    float4 qv = ((const float4*)embed_t)[((size_t)l*EE + id)*64 + lane];
    ((float4*)out)[rf*64 + lane] = qv;

    if (l == LL - 1) {
        float4 xv = ((const float4*)x)[rf*64 + lane];
        float dx = qv.x - xv.x, dy = qv.y - xv.y, dz = qv.z - xv.z, dw = qv.w - xv.w;
        float sq = dx*dx + dy*dy + dz*dz + dw*dw;
        #pragma unroll
        for (int off = 32; off; off >>= 1) sq += __shfl_down(sq, off);
        __shared__ float wsum[4];
        if (lane == 0) wsum[tid >> 6] = sq;
        __syncthreads();
        if (tid == 0) atomicAdd(diff_acc, wsum[0] + wsum[1] + wsum[2] + wsum[3]);
    }
}

// ---------------------------------------------------------------------------
// Kernel 4: new_cluster_size + per-l sum n  (counts now int)
// ---------------------------------------------------------------------------
__global__ void finalize_cluster_kernel(const float* __restrict__ cs_in,
                                        const int* __restrict__ counts_i,
                                        float* __restrict__ ncs_out,
                                        float* __restrict__ n_out) {
    const int l = blockIdx.x, tid = threadIdx.x;
    float s = 0.f;
    for (int e = tid; e < EE; e += 256) {
        float v = 0.999f*cs_in[l*EE + e] + 0.001f*(float)counts_i[l*EE + e];
        ncs_out[l*EE + e] = v;
        s += v;
    }
    #pragma unroll
    for (int off = 32; off; off >>= 1) s += __shfl_down(s, off);
    __shared__ float red[4];
    if ((tid & 63) == 0) red[tid >> 6] = s;
    __syncthreads();
    if (tid == 0) n_out[l] = red[0] + red[1] + red[2] + red[3];
}

// ---------------------------------------------------------------------------
// Kernel 5: new_embed_avg + new_embed
// ---------------------------------------------------------------------------
__global__ void finalize_embed_kernel(const float* __restrict__ embed_avg,
                                      const float* __restrict__ embed_sum,
                                      const float* __restrict__ ncs,
                                      const float* __restrict__ n,
                                      float* __restrict__ nea_out,
                                      float* __restrict__ ne_out) {
    __shared__ float tile[32][33];
    const int l  = blockIdx.z;
    const int d0 = blockIdx.y * 32;
    const int e0 = blockIdx.x * 32;
    const int tx = threadIdx.x, ty = threadIdx.y;

    tile[ty][tx] = embed_sum[((size_t)l*EE + e0 + ty)*DD + d0 + tx];
    __syncthreads();
    const size_t idx = ((size_t)l*DD + d0 + ty)*EE + e0 + tx;
    float nea = 0.999f*embed_avg[idx] + 0.001f*tile[tx][ty];
    nea_out[idx] = nea;
    float nl = n[l];
    float c  = ncs[l*EE + e0 + tx];
    float cs = (c + 1e-5f) / (nl + 0.02048f) * nl;
    ne_out[idx] = nea / cs;
}

// ---------------------------------------------------------------------------
// Kernel 6: diff scale
// ---------------------------------------------------------------------------
__global__ void diff_scale_kernel(const float* __restrict__ diff_acc,
                                  float* __restrict__ diff_out) {
    *diff_out = (*diff_acc / (float)(BB*SS*DD)) * 0.25f;
}

// ---------------------------------------------------------------------------
extern "C" void kernel_launch(void* const* d_in, const int* in_sizes, int n_in,
                              void* d_out, int out_size, void* d_ws, size_t ws_size,
                              hipStream_t stream) {
    const float* x            = (const float*)d_in[0];
    const float* embed        = (const float*)d_in[1];
    const float* cluster_size = (const float*)d_in[2];
    const float* embed_avg    = (const float*)d_in[3];

    float* out      = (float*)d_out;
    float* diff_out = out + 33554432;
    int*   ids_out  = (int*)(out + 33554433);
    float* ne_out   = out + 33685505;
    float* ncs_out  = out + 37879809;
    float* nea_out  = out + 37896193;

    float* ws        = (float*)d_ws;
    float* embed_t   = ws;                          // LED floats
    float* embed_sum = ws + LED;                    // LED floats (fully written by segsum)
    int*   counts_i  = (int*)(ws + 2*(size_t)LED);  // LE ints   (zeroed)
    float* norms     = ws + 2*(size_t)LED + LE;     // LE floats (zeroed)
    float* diff_acc  = norms + LE;                  // 1 float   (zeroed)
    float* n_ws      = diff_acc + 1;                // LL floats
    int*   bin_start = (int*)(n_ws + LL);           // LE ints
    int*   cursor    = bin_start + LE;              // LE ints
    int*   sorted_rows = cursor + LE;               // NROWS ints
    __bf16* embfrag  = (__bf16*)(sorted_rows + NROWS + 16);  // 8.9M bf16

    // zero: counts_i, norms, diff_acc (contiguous)
    hipMemsetAsync(counts_i, 0, (size_t)(2*LE + 1) * sizeof(float), stream);

    transpose_norms_kernel<<<dim3(EE/32, DD/32, LL), dim3(32, 32), 0, stream>>>(
        embed, embed_t, norms);

    prep_embed_frag<<<LL*64*NKS, 64, 0, stream>>>(embed, norms, embfrag);

    argmin_mfma<<<1024, 256, 0, stream>>>(x, embfrag, ids_out, counts_i);

    scan_kernel<<<LL, 256, 0, stream>>>(counts_i, bin_start, cursor);

    scatter_idx_kernel<<<NROWS/256, 256, 0, stream>>>(ids_out, cursor, sorted_rows);

    segsum_kernel<<<LE, 256, 0, stream>>>(x, sorted_rows, bin_start, counts_i, embed_sum);

    gather_out_kernel<<<NROWS/4, 256, 0, stream>>>(x, embed_t, ids_out, out, diff_acc);

    finalize_cluster_kernel<<<LL, 256, 0, stream>>>(cluster_size, counts_i, ncs_out, n_ws);

    finalize_embed_kernel<<<dim3(EE/32, DD/32, LL), dim3(32, 32), 0, stream>>>(
        embed_avg, embed_sum, ncs_out, n_ws, nea_out, ne_out);

    diff_scale_kernel<<<1, 1, 0, stream>>>(diff_acc, diff_out);
}